// Round 1
// baseline (179.676 us; speedup 1.0000x reference)
//
#include <hip/hip_runtime.h>

// Fused two-sided GraphSage-style embed + linear + dot.
// B=16384, MAX_DEG=50, D=64. One wave (64 lanes) per batch element,
// lane = embedding dim. 4 waves / 256-thread block.

constexpr int KDEG = 50;
constexpr int DIM  = 64;

// --- mask storage layout detection (bool dtype ambiguity) -------------------
// lay 0: int32 0/1   lay 1: uint8 0/1   lay 2: float32 0.0/1.0
__global__ void mask_layout_kernel(const unsigned char* __restrict__ mask,
                                   int* __restrict__ flag) {
  int lay = 0;
  for (int i = 0; i < 256; ++i) {
    unsigned char b = mask[i];
    if (b > 1) { lay = 2; break; }          // float32 exponent bytes (0x80/0x3F)
    if (b != 0 && (i & 3) != 0) lay = 1;    // nonzero off-word byte -> uint8
  }
  *flag = lay;
}

template <typename MT>
__device__ __forceinline__ void side_gather(
    const int* __restrict__ neibs, const MT* __restrict__ mask,
    const float* __restrict__ sel, const float* __restrict__ table,
    int base, int lane, float& acc, float& cnt)
{
  for (int k = 0; k < KDEG; ++k) {
    MT mv = mask[base + k];                 // wave-uniform value
    if (mv != (MT)0) {                      // uniform branch -> execz skip
      float s  = sel[base + k];
      int  idx = neibs[base + k];
      acc = fmaf(s, table[idx * DIM + lane], acc);
      cnt += 1.0f;
    }
  }
}

__global__ __launch_bounds__(256) void fused_graphsage_dot(
    const int* __restrict__ nodes_u, const int* __restrict__ nodes_v,
    const int* __restrict__ u_neibs, const int* __restrict__ v_neibs,
    const void* __restrict__ u_mask_p, const void* __restrict__ v_mask_p,
    const float* __restrict__ u_sel, const float* __restrict__ v_sel,
    const float* __restrict__ u2e, const float* __restrict__ v2e,
    const float* __restrict__ Wu, const float* __restrict__ bu,
    const float* __restrict__ Wv, const float* __restrict__ bv,
    const int* __restrict__ mflag, float* __restrict__ out)
{
  __shared__ float sm[4][256];
  const int lane = threadIdx.x & 63;
  const int wv   = threadIdx.x >> 6;
  const int i    = blockIdx.x * 4 + wv;     // grid sized exactly: B/4 blocks
  const int lay  = *mflag;
  const int base = i * KDEG;

  float self_u = u2e[nodes_u[i] * DIM + lane];
  float self_v = v2e[nodes_v[i] * DIM + lane];
  float acc_u = 0.f, cnt_u = 0.f, acc_v = 0.f, cnt_v = 0.f;

  if (lay == 0) {
    side_gather(u_neibs, (const int*)u_mask_p,          u_sel, u2e, base, lane, acc_u, cnt_u);
    side_gather(v_neibs, (const int*)v_mask_p,          v_sel, v2e, base, lane, acc_v, cnt_v);
  } else if (lay == 1) {
    side_gather(u_neibs, (const unsigned char*)u_mask_p, u_sel, u2e, base, lane, acc_u, cnt_u);
    side_gather(v_neibs, (const unsigned char*)v_mask_p, v_sel, v2e, base, lane, acc_v, cnt_v);
  } else {
    side_gather(u_neibs, (const float*)u_mask_p,         u_sel, u2e, base, lane, acc_u, cnt_u);
    side_gather(v_neibs, (const float*)v_mask_p,         v_sel, v2e, base, lane, acc_v, cnt_v);
  }

  // stage concat vectors for broadcast mat-vec
  sm[wv][lane]       = self_u;
  sm[wv][64 + lane]  = acc_u * (1.0f / fmaxf(cnt_u, 1.0f));
  sm[wv][128 + lane] = self_v;
  sm[wv][192 + lane] = acc_v * (1.0f / fmaxf(cnt_v, 1.0f));
  __syncthreads();

  float lin_u = bu[lane];
  float lin_v = bv[lane];
  #pragma unroll 8
  for (int d = 0; d < 128; ++d) {
    lin_u = fmaf(sm[wv][d],       Wu[d * DIM + lane], lin_u);
    lin_v = fmaf(sm[wv][128 + d], Wv[d * DIM + lane], lin_v);
  }

  float Ue = (cnt_u > 0.f) ? lin_u : self_u;   // deg==0 -> raw self embedding
  float Ve = (cnt_v > 0.f) ? lin_v : self_v;

  float p = Ue * Ve;
  #pragma unroll
  for (int off = 32; off > 0; off >>= 1) p += __shfl_xor(p, off, 64);
  if (lane == 0) out[i] = p;
}

extern "C" void kernel_launch(void* const* d_in, const int* in_sizes, int n_in,
                              void* d_out, int out_size, void* d_ws, size_t ws_size,
                              hipStream_t stream) {
  const int*   nodes_u = (const int*)  d_in[0];
  const int*   nodes_v = (const int*)  d_in[1];
  const int*   u_neibs = (const int*)  d_in[2];
  const int*   v_neibs = (const int*)  d_in[3];
  const void*  u_mask  =               d_in[4];
  const void*  v_mask  =               d_in[5];
  const float* u_sel   = (const float*)d_in[6];
  const float* v_sel   = (const float*)d_in[7];
  const float* u2e     = (const float*)d_in[8];
  const float* v2e     = (const float*)d_in[9];
  const float* Wu      = (const float*)d_in[10];
  const float* bu      = (const float*)d_in[11];
  const float* Wv      = (const float*)d_in[12];
  const float* bv      = (const float*)d_in[13];
  float* out = (float*)d_out;

  const int batch = in_sizes[0];           // 16384
  int* flag = (int*)d_ws;

  mask_layout_kernel<<<1, 1, 0, stream>>>((const unsigned char*)u_mask, flag);
  fused_graphsage_dot<<<batch / 4, 256, 0, stream>>>(
      nodes_u, nodes_v, u_neibs, v_neibs, u_mask, v_mask, u_sel, v_sel,
      u2e, v2e, Wu, bu, Wv, bv, flag, out);
}

// Round 2
// 83.181 us; speedup vs baseline: 2.1601x; 2.1601x over previous
//
#include <hip/hip_runtime.h>

// Fused two-sided GraphSage-style embed + linear + dot.
// B=16384, MAX_DEG=50, D=64. One wave per batch element, 4 waves/block.
// Gather phase: lane-parallel metadata load -> wave compaction (ballot) ->
// 13 fully-unrolled rounds of float4 gathers (4 rows per wave-instruction).

constexpr int KDEG   = 50;
constexpr int DIM    = 64;
constexpr int SLOTS  = 52;            // KDEG padded to multiple of 4
constexpr int ROUNDS = SLOTS / 4;     // 13
constexpr int SSTR   = 56;            // LDS slot stride (padding)

// --- mask storage layout detection (bool dtype ambiguity) -------------------
// lay 0: int32 0/1   lay 1: uint8 0/1   lay 2: float32 0.0/1.0
__global__ void mask_layout_kernel(const unsigned char* __restrict__ mask,
                                   int* __restrict__ flag) {
  int lay = 0;
  for (int i = 0; i < 256; ++i) {
    unsigned char b = mask[i];
    if (b > 1) { lay = 2; break; }          // float32 exponent bytes
    if (b != 0 && (i & 3) != 0) lay = 1;    // nonzero off-word byte -> uint8
  }
  *flag = lay;
}

template <typename MT>
__device__ __forceinline__ void load_meta(const void* __restrict__ mask_p,
                                          const float* __restrict__ sel,
                                          const int* __restrict__ neibs,
                                          int base, int lane,
                                          int& idx, float& w, bool& act) {
  if (lane < KDEG) {
    MT m   = ((const MT*)mask_p)[base + lane];
    float s = sel[base + lane];
    idx    = neibs[base + lane];
    act    = (m != (MT)0);
    w      = act ? s : 0.0f;
  } else { idx = 0; w = 0.0f; act = false; }
}

// Compact active (idx,w) pairs into slots [0,cnt); fill [cnt,SLOTS) with zeros.
__device__ __forceinline__ int compact_side(int lane, int idx, float w, bool act,
                                            int* __restrict__ sidx,
                                            float* __restrict__ sw) {
  unsigned long long balA = __ballot(act);
  unsigned long long balI = __ballot(!act && (lane < SLOTS));
  int cnt = __popcll(balA);
  unsigned long long below = (1ULL << lane) - 1ULL;
  int pos = act ? __popcll(balA & below)
                : cnt + __popcll(balI & below);
  if (lane < SLOTS) {                     // act implies lane<50<SLOTS
    sidx[pos] = act ? idx : 0;
    sw[pos]   = act ? w   : 0.0f;
  }
  return cnt;
}

__device__ __forceinline__ float4 gather_rounds(const float* __restrict__ table,
                                                const int* __restrict__ sidx,
                                                const float* __restrict__ sw,
                                                int sub, int t) {
  float4 acc = make_float4(0.f, 0.f, 0.f, 0.f);
  #pragma unroll
  for (int r = 0; r < ROUNDS; ++r) {
    int   slot = r * 4 + sub;
    int   gi   = sidx[slot];              // LDS broadcast within 16-lane group
    float gw   = sw[slot];
    float4 v = ((const float4*)(table + (size_t)gi * DIM))[t];
    acc.x = fmaf(gw, v.x, acc.x);
    acc.y = fmaf(gw, v.y, acc.y);
    acc.z = fmaf(gw, v.z, acc.z);
    acc.w = fmaf(gw, v.w, acc.w);
  }
  return acc;
}

__global__ __launch_bounds__(256) void fused_graphsage_dot(
    const int* __restrict__ nodes_u, const int* __restrict__ nodes_v,
    const int* __restrict__ u_neibs, const int* __restrict__ v_neibs,
    const void* __restrict__ u_mask_p, const void* __restrict__ v_mask_p,
    const float* __restrict__ u_sel, const float* __restrict__ v_sel,
    const float* __restrict__ u2e, const float* __restrict__ v2e,
    const float* __restrict__ Wu, const float* __restrict__ bu,
    const float* __restrict__ Wv, const float* __restrict__ bv,
    const int* __restrict__ mflag, float* __restrict__ out)
{
  __shared__ int   sidx[4][2][SSTR];
  __shared__ float sw  [4][2][SSTR];
  __shared__ float sx  [4][256];          // concat vectors: [u_self|u_agg|v_self|v_agg]

  const int lane = threadIdx.x & 63;
  const int wv   = threadIdx.x >> 6;
  const int i    = blockIdx.x * 4 + wv;
  const int lay  = *mflag;
  const int base = i * KDEG;
  const int sub  = lane >> 4, t = lane & 15;

  // --- lane-parallel metadata + compaction ---
  int iu, iv; float wu_, wv_; bool au, av;
  if (lay == 0) {
    load_meta<int>(u_mask_p, u_sel, u_neibs, base, lane, iu, wu_, au);
    load_meta<int>(v_mask_p, v_sel, v_neibs, base, lane, iv, wv_, av);
  } else if (lay == 1) {
    load_meta<unsigned char>(u_mask_p, u_sel, u_neibs, base, lane, iu, wu_, au);
    load_meta<unsigned char>(v_mask_p, v_sel, v_neibs, base, lane, iv, wv_, av);
  } else {
    load_meta<float>(u_mask_p, u_sel, u_neibs, base, lane, iu, wu_, au);
    load_meta<float>(v_mask_p, v_sel, v_neibs, base, lane, iv, wv_, av);
  }
  int cnt_u = compact_side(lane, iu, wu_, au, sidx[wv][0], sw[wv][0]);
  int cnt_v = compact_side(lane, iv, wv_, av, sidx[wv][1], sw[wv][1]);

  float self_u = u2e[(size_t)nodes_u[i] * DIM + lane];
  float self_v = v2e[(size_t)nodes_v[i] * DIM + lane];

  __syncthreads();

  // --- pipelined float4 gathers: 4 rows per wave-instruction ---
  float4 agg_u = gather_rounds(u2e, sidx[wv][0], sw[wv][0], sub, t);
  float4 agg_v = gather_rounds(v2e, sidx[wv][1], sw[wv][1], sub, t);

  // reduce the 4 subgroup partials (butterfly over lane bits 4,5)
  #pragma unroll
  for (int off = 16; off <= 32; off <<= 1) {
    agg_u.x += __shfl_xor(agg_u.x, off, 64);
    agg_u.y += __shfl_xor(agg_u.y, off, 64);
    agg_u.z += __shfl_xor(agg_u.z, off, 64);
    agg_u.w += __shfl_xor(agg_u.w, off, 64);
    agg_v.x += __shfl_xor(agg_v.x, off, 64);
    agg_v.y += __shfl_xor(agg_v.y, off, 64);
    agg_v.z += __shfl_xor(agg_v.z, off, 64);
    agg_v.w += __shfl_xor(agg_v.w, off, 64);
  }

  const float inv_u = 1.0f / fmaxf((float)cnt_u, 1.0f);
  const float inv_v = 1.0f / fmaxf((float)cnt_v, 1.0f);

  // --- stage concat vectors ---
  sx[wv][lane]       = self_u;
  sx[wv][128 + lane] = self_v;
  if (sub == 0) {     // lanes 0..15 hold the reduced agg
    float4 a = make_float4(agg_u.x * inv_u, agg_u.y * inv_u,
                           agg_u.z * inv_u, agg_u.w * inv_u);
    float4 b = make_float4(agg_v.x * inv_v, agg_v.y * inv_v,
                           agg_v.z * inv_v, agg_v.w * inv_v);
    ((float4*)&sx[wv][64])[t]  = a;
    ((float4*)&sx[wv][192])[t] = b;
  }
  __syncthreads();

  // --- mat-vec: lane = output dim ---
  float lin_u = bu[lane];
  float lin_v = bv[lane];
  #pragma unroll 8
  for (int d = 0; d < 128; ++d) {
    lin_u = fmaf(sx[wv][d],       Wu[d * DIM + lane], lin_u);
    lin_v = fmaf(sx[wv][128 + d], Wv[d * DIM + lane], lin_v);
  }

  float Ue = (cnt_u > 0) ? lin_u : self_u;
  float Ve = (cnt_v > 0) ? lin_v : self_v;

  float p = Ue * Ve;
  #pragma unroll
  for (int off = 32; off > 0; off >>= 1) p += __shfl_xor(p, off, 64);
  if (lane == 0) out[i] = p;
}

extern "C" void kernel_launch(void* const* d_in, const int* in_sizes, int n_in,
                              void* d_out, int out_size, void* d_ws, size_t ws_size,
                              hipStream_t stream) {
  const int*   nodes_u = (const int*)  d_in[0];
  const int*   nodes_v = (const int*)  d_in[1];
  const int*   u_neibs = (const int*)  d_in[2];
  const int*   v_neibs = (const int*)  d_in[3];
  const void*  u_mask  =               d_in[4];
  const void*  v_mask  =               d_in[5];
  const float* u_sel   = (const float*)d_in[6];
  const float* v_sel   = (const float*)d_in[7];
  const float* u2e     = (const float*)d_in[8];
  const float* v2e     = (const float*)d_in[9];
  const float* Wu      = (const float*)d_in[10];
  const float* bu      = (const float*)d_in[11];
  const float* Wv      = (const float*)d_in[12];
  const float* bv      = (const float*)d_in[13];
  float* out = (float*)d_out;

  const int batch = in_sizes[0];           // 16384
  int* flag = (int*)d_ws;

  mask_layout_kernel<<<1, 1, 0, stream>>>((const unsigned char*)u_mask, flag);
  fused_graphsage_dot<<<batch / 4, 256, 0, stream>>>(
      nodes_u, nodes_v, u_neibs, v_neibs, u_mask, v_mask, u_sel, v_sel,
      u2e, v2e, Wu, bu, Wv, bv, flag, out);
}